// Round 7
// baseline (265.390 us; speedup 1.0000x reference)
//
#include <hip/hip_runtime.h>
#include <stdint.h>

// MultiHeadAttention: x[4,2048,1024] fp32; Wq/Wk/Wv/Wo [1024,1024]; biases zero.
// out = softmax((xWq^T)(xWk^T)^T / 32) (xWv^T) Wo^T + bo   (16 heads, d=64)
//
// Pipeline (bf16 MFMA, fp32 accum):
//  k_cvt_all: x,W* fp32->bf16 (single fused launch)
//  k_gemm3: fused QKV projection, N=3072 (Wq/Wk/Wv contiguous in ws):
//     Q -> [bh][tok][64] pre-scaled by log2e/32; K -> [bh][tok][64];
//     V -> [bh][64][tok] transposed
//  k_attn: flash-style, swapped-S^T MFMA, 32KB LDS single-buffer,
//     T14 reg-staged prefetch (K at loop top, V after S-phase; ds_write
//     after the tile barrier) — hides global latency w/o LDS dbuf cost.
//     den via MFMA(ones). launch_bounds(256,4) (r4: (256,5) spills).
//  k_gemmo: O @ Wo^T + bo -> fp32 d_out

#define HID 1024
#define NH 16
#define HD 64
#define BB 4
#define SEQ 2048
#define MTOT (BB * SEQ) // 8192

typedef short bf16x8 __attribute__((ext_vector_type(8)));
typedef float f32x4 __attribute__((ext_vector_type(4)));

// swizzle: byte col within a 128B row, XORed by row&7 -> conflict-free b128
#define SWZ(row, cb) ((cb) ^ (((row) & 7) << 4))

#define GLDS(gp, lp) __builtin_amdgcn_global_load_lds( \
    (const __attribute__((address_space(1))) void*)(gp), \
    (__attribute__((address_space(3))) void*)(lp), 16, 0, 0)

static __device__ __forceinline__ unsigned short f2bf(float f) {
  unsigned u = __float_as_uint(f);
  u += 0x7fffu + ((u >> 16) & 1u); // RNE
  return (unsigned short)(u >> 16);
}

static __device__ __forceinline__ f32x4 mfma16(bf16x8 a, bf16x8 b, f32x4 c) {
  return __builtin_amdgcn_mfma_f32_16x16x32_bf16(a, b, c, 0, 0, 0);
}

// ---------------- fp32 -> bf16 convert, all tensors, one launch ----------------
__global__ void k_cvt_all(const float* __restrict__ x,
                          const float* __restrict__ Wq, const float* __restrict__ Wk,
                          const float* __restrict__ Wv, const float* __restrict__ Wo,
                          unsigned short* __restrict__ ws) {
  const int X4 = MTOT * HID / 4;  // 2097152
  const int W4 = HID * HID / 4;   // 262144
  int i = blockIdx.x * blockDim.x + threadIdx.x; // total X4 + 4*W4 = 3145728
  const float* src;
  unsigned short* dst;
  int off;
  if (i < X4) {
    src = x; dst = ws; off = i;
  } else {
    int j = i - X4;
    int w = j / W4;
    off = j - w * W4;
    src = (w == 0) ? Wq : (w == 1) ? Wk : (w == 2) ? Wv : Wo;
    dst = ws + (size_t)MTOT * HID + (size_t)w * HID * HID;
  }
  float4 v = reinterpret_cast<const float4*>(src)[off];
  ushort4 o;
  o.x = f2bf(v.x); o.y = f2bf(v.y); o.z = f2bf(v.z); o.w = f2bf(v.w);
  reinterpret_cast<ushort4*>(dst)[off] = o;
}

// ---------------- fused QKV GEMM: [8192,3072] = A[M,K] @ W3[3N,K]^T ----------------
// 128x128 tile, BK=64, 4 waves (2x2). global_load_lds dwordx4, linear LDS.
__global__ __launch_bounds__(256, 2) void k_gemm3(
    const unsigned short* __restrict__ A,
    const unsigned short* __restrict__ W3,   // [3072][1024] = Wq;Wk;Wv rows
    const float* __restrict__ bq, const float* __restrict__ bk,
    const float* __restrict__ bv,
    unsigned short* __restrict__ Qo,   // [64][2048][64]
    unsigned short* __restrict__ Ko,   // [64][2048][64]
    unsigned short* __restrict__ Vto,  // [64][64][2048]
    float cexp) {
  const int K = HID;
  __shared__ __align__(16) unsigned short sA[128 * 64];
  __shared__ __align__(16) unsigned short sB[128 * 64];
  const int m0 = blockIdx.x * 128;
  const int n0 = blockIdx.y * 128; // 0..2944
  const int tid = threadIdx.x;
  const int lane = tid & 63, wid = tid >> 6;
  const int wr = wid >> 1, wc = wid & 1;
  const int lr = lane & 15, lg = lane >> 4;

  f32x4 acc[4][4] = {};

  const unsigned short* gA = A + (size_t)m0 * K;
  const unsigned short* gW = W3 + (size_t)n0 * K;

  for (int kt = 0; kt < K; kt += 64) {
#pragma unroll
    for (int i = 0; i < 4; ++i) {
      int c = tid + i * 256;
      int row = c >> 3, col = (c & 7) << 3;
      GLDS(gA + (size_t)row * K + kt + col, (char*)sA + (size_t)c * 16);
      GLDS(gW + (size_t)row * K + kt + col, (char*)sB + (size_t)c * 16);
    }
    __syncthreads();
#pragma unroll
    for (int kk = 0; kk < 64; kk += 32) {
      bf16x8 a[4], b[4];
      const int co = kk + lg * 8;
#pragma unroll
      for (int m = 0; m < 4; ++m)
        a[m] = *reinterpret_cast<const bf16x8*>(sA + (wr * 64 + m * 16 + lr) * 64 + co);
#pragma unroll
      for (int n = 0; n < 4; ++n)
        b[n] = *reinterpret_cast<const bf16x8*>(sB + (wc * 64 + n * 16 + lr) * 64 + co);
      __builtin_amdgcn_s_setprio(1);
#pragma unroll
      for (int m = 0; m < 4; ++m)
#pragma unroll
        for (int n = 0; n < 4; ++n)
          acc[m][n] = mfma16(a[m], b[n], acc[m][n]);
      __builtin_amdgcn_s_setprio(0);
    }
    __syncthreads();
  }

  const int sect = n0 >> 10; // 0=Q 1=K 2=V
  const float* bias = (sect == 0) ? bq : (sect == 1) ? bk : bv;
  const float sc = (sect == 0) ? cexp : 1.0f;

  if (sect < 2) {
    unsigned short* C = (sect == 0) ? Qo : Ko;
#pragma unroll
    for (int m = 0; m < 4; ++m) {
      int row0 = m0 + wr * 64 + m * 16 + lg * 4;
      int b = row0 >> 11;
#pragma unroll
      for (int n = 0; n < 4; ++n) {
        int colq = (n0 + wc * 64 + n * 16 + lr) & 1023;
        float bvv = bias[colq];
        int h = colq >> 6, d = colq & 63;
        size_t base = ((size_t)(b * NH + h) * SEQ) * HD + d;
#pragma unroll
        for (int r = 0; r < 4; ++r) {
          int tok = (row0 + r) & 2047;
          C[base + (size_t)tok * HD] = f2bf((acc[m][n][r] + bvv) * sc);
        }
      }
    }
  } else {
#pragma unroll
    for (int m = 0; m < 4; ++m) {
      int row0 = m0 + wr * 64 + m * 16 + lg * 4;
      int b = row0 >> 11;
      int tok0 = row0 & 2047;
#pragma unroll
      for (int n = 0; n < 4; ++n) {
        int colq = (n0 + wc * 64 + n * 16 + lr) & 1023;
        float bvv = bias[colq];
        int h = colq >> 6, d = colq & 63;
        ushort4 pk;
        pk.x = f2bf(acc[m][n][0] + bvv);
        pk.y = f2bf(acc[m][n][1] + bvv);
        pk.z = f2bf(acc[m][n][2] + bvv);
        pk.w = f2bf(acc[m][n][3] + bvv);
        *reinterpret_cast<ushort4*>(&Vto[((size_t)(b * NH + h) * HD + d) * SEQ + tok0]) = pk;
      }
    }
  }
}

// ---------------- out-proj GEMM: fp32 out = O @ Wo^T + bo ----------------
__global__ __launch_bounds__(256, 2) void k_gemmo(
    const unsigned short* __restrict__ A,
    const unsigned short* __restrict__ W,
    const float* __restrict__ bias,
    float* __restrict__ C) {
  const int K = HID;
  __shared__ __align__(16) unsigned short sA[128 * 64];
  __shared__ __align__(16) unsigned short sB[128 * 64];
  const int m0 = blockIdx.x * 128;
  const int n0 = blockIdx.y * 128;
  const int tid = threadIdx.x;
  const int lane = tid & 63, wid = tid >> 6;
  const int wr = wid >> 1, wc = wid & 1;
  const int lr = lane & 15, lg = lane >> 4;

  f32x4 acc[4][4] = {};

  const unsigned short* gA = A + (size_t)m0 * K;
  const unsigned short* gW = W + (size_t)n0 * K;

  for (int kt = 0; kt < K; kt += 64) {
#pragma unroll
    for (int i = 0; i < 4; ++i) {
      int c = tid + i * 256;
      int row = c >> 3, col = (c & 7) << 3;
      GLDS(gA + (size_t)row * K + kt + col, (char*)sA + (size_t)c * 16);
      GLDS(gW + (size_t)row * K + kt + col, (char*)sB + (size_t)c * 16);
    }
    __syncthreads();
#pragma unroll
    for (int kk = 0; kk < 64; kk += 32) {
      bf16x8 a[4], b[4];
      const int co = kk + lg * 8;
#pragma unroll
      for (int m = 0; m < 4; ++m)
        a[m] = *reinterpret_cast<const bf16x8*>(sA + (wr * 64 + m * 16 + lr) * 64 + co);
#pragma unroll
      for (int n = 0; n < 4; ++n)
        b[n] = *reinterpret_cast<const bf16x8*>(sB + (wc * 64 + n * 16 + lr) * 64 + co);
      __builtin_amdgcn_s_setprio(1);
#pragma unroll
      for (int m = 0; m < 4; ++m)
#pragma unroll
        for (int n = 0; n < 4; ++n)
          acc[m][n] = mfma16(a[m], b[n], acc[m][n]);
      __builtin_amdgcn_s_setprio(0);
    }
    __syncthreads();
  }

#pragma unroll
  for (int m = 0; m < 4; ++m) {
    int row0 = m0 + wr * 64 + m * 16 + lg * 4;
#pragma unroll
    for (int n = 0; n < 4; ++n) {
      int col = n0 + wc * 64 + n * 16 + lr;
      float bvv = bias[col];
#pragma unroll
      for (int r = 0; r < 4; ++r)
        C[(size_t)(row0 + r) * HID + col] = acc[m][n][r] + bvv;
    }
  }
}

// ---------------- attention ----------------
// grid (bh=64, qt=16); 4 waves; wave owns 32 q-rows. KVB=64, single LDS buffer.
// T14: next K tile loaded to regs at loop top, next V after S-phase; ds_write
// (swizzled dest) after the end-of-tile barrier, then one more barrier.
// den: accd[m] += mfma(pa[m], ones) -> same fragment layout as acco.
#define KVB 64
#define NT (SEQ / KVB) // 32

__global__ __launch_bounds__(256, 4) void k_attn(
    const unsigned short* __restrict__ Qg,  // [64][2048][64]
    const unsigned short* __restrict__ Kg,  // [64][2048][64]
    const unsigned short* __restrict__ Vt,  // [64][64][2048]
    unsigned short* __restrict__ Og) {      // [8192][1024] bf16
  __shared__ __align__(16) unsigned short sP[128 * 64]; // 16KB (Q staged here first)
  __shared__ __align__(16) unsigned short sK[KVB * 64]; //  8KB
  __shared__ __align__(16) unsigned short sV[KVB * 64]; //  8KB

  const int bh = blockIdx.x;
  const int qt = blockIdx.y;
  const int tid = threadIdx.x;
  const int lane = tid & 63, wid = tid >> 6;
  const int lr = lane & 15, lg = lane >> 4;

  const unsigned short* Qh = Qg + ((size_t)bh * SEQ + (size_t)qt * 128) * HD;
  const unsigned short* Kh = Kg + (size_t)bh * SEQ * HD;
  const unsigned short* Vh = Vt + (size_t)bh * HD * SEQ;

  // staging geometry: thread covers chunks c0=tid (row r0) and c1=tid+256 (row r0+32)
  const int r0 = tid >> 3, r1 = r0 + 32;
  const int cls = (tid & 7) * 8;              // short col offset (16B aligned)
  const int dK0 = r0 * 128 + SWZ(r0, (tid & 7) << 4); // swizzled LDS byte offsets
  const int dK1 = r1 * 128 + SWZ(r1, (tid & 7) << 4);

  // prologue: Q tile + K/V tile 0 via global_load_lds (pre-swizzled source)
#pragma unroll
  for (int i = 0; i < 4; ++i) {
    int c = tid + i * 256;
    int row = c >> 3;
    int cbl = SWZ(row, (c & 7) << 4);
    GLDS(Qh + (size_t)row * HD + (cbl >> 1), (char*)sP + (size_t)c * 16);
  }
  {
    int cb0 = SWZ(r0, (tid & 7) << 4) >> 1, cb1 = SWZ(r1, (tid & 7) << 4) >> 1;
    GLDS(Kh + (size_t)r0 * HD + cb0, (char*)sK + (size_t)tid * 16);
    GLDS(Kh + (size_t)r1 * HD + cb1, (char*)sK + (size_t)(tid + 256) * 16);
    GLDS(Vh + (size_t)r0 * SEQ + cb0, (char*)sV + (size_t)tid * 16);
    GLDS(Vh + (size_t)r1 * SEQ + cb1, (char*)sV + (size_t)(tid + 256) * 16);
  }
  __syncthreads(); // Q + tile0 visible

  bf16x8 qb[2][2];
#pragma unroll
  for (int m = 0; m < 2; ++m)
#pragma unroll
    for (int kd = 0; kd < 2; ++kd) {
      int row = wid * 32 + m * 16 + lr;
      qb[m][kd] = *reinterpret_cast<const bf16x8*>(
          (const char*)sP + row * 128 + SWZ(lr, kd * 64 + lg * 16));
    }
  // sP now per-wave-row private (P writes/reads own 32-row band only)

  const unsigned short onev = (unsigned short)0x3F80; // bf16 1.0
  const bf16x8 ones = {(short)onev, (short)onev, (short)onev, (short)onev,
                       (short)onev, (short)onev, (short)onev, (short)onev};

  f32x4 acco[2][4] = {};
  f32x4 accd[2] = {};

  for (int t = 0; t < NT; ++t) {
    // T14 stage-issue: next K tile -> regs (consumed after the tile barrier)
    uint4 kr0, kr1, vr0, vr1;
    const bool pf = (t + 1 < NT);
    if (pf) {
      const int ktn = (t + 1) * KVB;
      kr0 = *reinterpret_cast<const uint4*>(Kh + (size_t)(ktn + r0) * HD + cls);
      kr1 = *reinterpret_cast<const uint4*>(Kh + (size_t)(ktn + r1) * HD + cls);
    }

    // S^T = K Q^T : accs[m][n]: kv = n*16+4lg+r, q = wid*32+m*16+lr
    f32x4 accs[2][4] = {};
#pragma unroll
    for (int kd = 0; kd < 2; ++kd) {
      bf16x8 ka[4];
#pragma unroll
      for (int n = 0; n < 4; ++n)
        ka[n] = *reinterpret_cast<const bf16x8*>(
            (const char*)sK + (n * 16 + lr) * 128 + SWZ(lr, kd * 64 + lg * 16));
      __builtin_amdgcn_s_setprio(1);
#pragma unroll
      for (int n = 0; n < 4; ++n) {
        accs[0][n] = mfma16(ka[n], qb[0][kd], accs[0][n]);
        accs[1][n] = mfma16(ka[n], qb[1][kd], accs[1][n]);
      }
      __builtin_amdgcn_s_setprio(0);
    }

    // T14 stage-issue: next V tile -> regs (overlaps P + PV below)
    if (pf) {
      const int ktn = (t + 1) * KVB;
      vr0 = *reinterpret_cast<const uint4*>(Vh + (size_t)r0 * SEQ + ktn + cls);
      vr1 = *reinterpret_cast<const uint4*>(Vh + (size_t)r1 * SEQ + ktn + cls);
    }

    // P = exp2(S^T) -> packed bf16 swizzled b64 write to sP[q][kv] (own rows)
#pragma unroll
    for (int m = 0; m < 2; ++m) {
      const int q = wid * 32 + m * 16 + lr;
#pragma unroll
      for (int n = 0; n < 4; ++n) {
        float p0 = exp2f(accs[m][n][0]);
        float p1 = exp2f(accs[m][n][1]);
        float p2 = exp2f(accs[m][n][2]);
        float p3 = exp2f(accs[m][n][3]);
        unsigned w0, w1;
        asm("v_cvt_pk_bf16_f32 %0, %1, %2" : "=v"(w0) : "v"(p0), "v"(p1));
        asm("v_cvt_pk_bf16_f32 %0, %1, %2" : "=v"(w1) : "v"(p2), "v"(p3));
        uint2 pk; pk.x = w0; pk.y = w1;
        *reinterpret_cast<uint2*>((char*)sP + q * 128 + SWZ(q, n * 32 + lg * 8)) = pk;
      }
    }

    // O += P V ; den += P * ones
#pragma unroll
    for (int js = 0; js < 2; ++js) {
      bf16x8 pa[2], vb[4];
#pragma unroll
      for (int m = 0; m < 2; ++m) {
        int row = wid * 32 + m * 16 + lr;
        pa[m] = *reinterpret_cast<const bf16x8*>(
            (const char*)sP + row * 128 + SWZ(lr, js * 64 + lg * 16));
      }
#pragma unroll
      for (int n = 0; n < 4; ++n)
        vb[n] = *reinterpret_cast<const bf16x8*>(
            (const char*)sV + (n * 16 + lr) * 128 + SWZ(lr, js * 64 + lg * 16));
      __builtin_amdgcn_s_setprio(1);
#pragma unroll
      for (int m = 0; m < 2; ++m) {
#pragma unroll
        for (int n = 0; n < 4; ++n)
          acco[m][n] = mfma16(pa[m], vb[n], acco[m][n]);
        accd[m] = mfma16(pa[m], ones, accd[m]);
      }
      __builtin_amdgcn_s_setprio(0);
    }

    if (pf) {
      __syncthreads(); // all waves done reading sK/sV for tile t
      // write staged regs (compiler inserts vmcnt wait on kr/vr here)
      *reinterpret_cast<uint4*>((char*)sK + dK0) = kr0;
      *reinterpret_cast<uint4*>((char*)sK + dK1) = kr1;
      *reinterpret_cast<uint4*>((char*)sV + dK0) = vr0;
      *reinterpret_cast<uint4*>((char*)sV + dK1) = vr1;
      __syncthreads(); // tile t+1 visible
    }
  }

  // rden directly from accd (identical fragment layout to acco)
  const int b = bh >> 4, h = bh & 15;
#pragma unroll
  for (int m = 0; m < 2; ++m) {
    int tok0 = qt * 128 + wid * 32 + m * 16 + lg * 4;
#pragma unroll
    for (int r = 0; r < 4; ++r) {
      float rd = 1.0f / accd[m][r];
#pragma unroll
      for (int n = 0; n < 4; ++n) {
        int col = h * 64 + n * 16 + lr;
        Og[(size_t)(b * SEQ + tok0 + r) * HID + col] = f2bf(acco[m][n][r] * rd);
      }
    }
  }
}

// ---------------- launch ----------------
extern "C" void kernel_launch(void* const* d_in, const int* in_sizes, int n_in,
                              void* d_out, int out_size, void* d_ws, size_t ws_size,
                              hipStream_t stream) {
  (void)in_sizes; (void)n_in; (void)out_size; (void)ws_size;
  const float* x = (const float*)d_in[0];
  const float* Wq = (const float*)d_in[1];
  const float* bq = (const float*)d_in[2];
  const float* Wk = (const float*)d_in[3];
  const float* bk = (const float*)d_in[4];
  const float* Wv = (const float*)d_in[5];
  const float* bv = (const float*)d_in[6];
  const float* Wo = (const float*)d_in[7];
  const float* bo = (const float*)d_in[8];

  unsigned short* ws = (unsigned short*)d_ws;
  unsigned short* xb = ws;
  unsigned short* wqb = xb + (size_t)MTOT * HID;  // Wq;Wk;Wv;Wo contiguous
  unsigned short* wob = wqb + 3 * (size_t)HID * HID;
  unsigned short* qb = wob + (size_t)HID * HID;   // [64][2048][64]
  unsigned short* kb = qb + (size_t)MTOT * HID;   // [64][2048][64]
  unsigned short* vtb = kb + (size_t)MTOT * HID;  // [64][64][2048]
  unsigned short* ob = vtb + (size_t)MTOT * HID;  // [8192][1024]

  const float cexp = 0.04508422f; // log2(e)/32

  k_cvt_all<<<(MTOT * HID / 4 + 4 * (HID * HID / 4)) / 256, 256, 0, stream>>>(
      x, Wq, Wk, Wv, Wo, ws);

  k_gemm3<<<dim3(MTOT / 128, 3 * HID / 128), 256, 0, stream>>>(
      xb, wqb, bq, bk, bv, qb, kb, vtb, cexp);

  k_attn<<<dim3(64, SEQ / 128), 256, 0, stream>>>(qb, kb, vtb, ob);

  k_gemmo<<<dim3(MTOT / 128, HID / 128), 256, 0, stream>>>(ob, wob, bo, (float*)d_out);
}

// Round 8
// 211.935 us; speedup vs baseline: 1.2522x; 1.2522x over previous
//
#include <hip/hip_runtime.h>
#include <stdint.h>

// MultiHeadAttention: x[4,2048,1024] fp32; Wq/Wk/Wv/Wo [1024,1024]; biases zero.
// out = softmax((xWq^T)(xWk^T)^T / 32) (xWv^T) Wo^T + bo   (16 heads, d=64)
//
// Pipeline (bf16 MFMA, fp32 accum):
//  k_cvt_all: x,W* fp32->bf16 (single fused launch)
//  k_gemm3: fused QKV projection, N=3072, XCD-partitioned grid
//  k_attn:  flash-style, swapped-S^T MFMA, 32KB LDS single-buffer, in-loop
//           global_load_lds staging (r5 structure = proven 126us; r6 LDS-dbuf
//           and r7 reg-dbuf both regressed via occupancy/serialization),
//           den via MFMA(ones).
//  k_gemmo: O @ Wo^T + bo -> fp32 d_out, XCD-partitioned grid

#define HID 1024
#define NH 16
#define HD 64
#define BB 4
#define SEQ 2048
#define MTOT (BB * SEQ) // 8192

typedef short bf16x8 __attribute__((ext_vector_type(8)));
typedef float f32x4 __attribute__((ext_vector_type(4)));

// swizzle: byte col within a 128B row, XORed by row&7 -> conflict-free b128
#define SWZ(row, cb) ((cb) ^ (((row) & 7) << 4))

#define GLDS(gp, lp) __builtin_amdgcn_global_load_lds( \
    (const __attribute__((address_space(1))) void*)(gp), \
    (__attribute__((address_space(3))) void*)(lp), 16, 0, 0)

static __device__ __forceinline__ unsigned short f2bf(float f) {
  unsigned u = __float_as_uint(f);
  u += 0x7fffu + ((u >> 16) & 1u); // RNE
  return (unsigned short)(u >> 16);
}

static __device__ __forceinline__ f32x4 mfma16(bf16x8 a, bf16x8 b, f32x4 c) {
  return __builtin_amdgcn_mfma_f32_16x16x32_bf16(a, b, c, 0, 0, 0);
}

// ---------------- fp32 -> bf16 convert, all tensors, one launch ----------------
__global__ void k_cvt_all(const float* __restrict__ x,
                          const float* __restrict__ Wq, const float* __restrict__ Wk,
                          const float* __restrict__ Wv, const float* __restrict__ Wo,
                          unsigned short* __restrict__ ws) {
  const int X4 = MTOT * HID / 4;  // 2097152
  const int W4 = HID * HID / 4;   // 262144
  int i = blockIdx.x * blockDim.x + threadIdx.x;
  const float* src;
  unsigned short* dst;
  int off;
  if (i < X4) {
    src = x; dst = ws; off = i;
  } else {
    int j = i - X4;
    int w = j / W4;
    off = j - w * W4;
    src = (w == 0) ? Wq : (w == 1) ? Wk : (w == 2) ? Wv : Wo;
    dst = ws + (size_t)MTOT * HID + (size_t)w * HID * HID;
  }
  float4 v = reinterpret_cast<const float4*>(src)[off];
  ushort4 o;
  o.x = f2bf(v.x); o.y = f2bf(v.y); o.z = f2bf(v.z); o.w = f2bf(v.w);
  reinterpret_cast<ushort4*>(dst)[off] = o;
}

// ---------------- fused QKV GEMM: [8192,3072] = A[M,K] @ W3[3N,K]^T ----------------
// 128x128 tile, BK=64, 4 waves (2x2). global_load_lds dwordx4, linear LDS.
// Grid XCD-partitioned: 8 rectangles (4 m-groups x 2 n-groups), m-minor inside,
// so each XCD's L2 holds a 4MB A-slab + small B panels (kills A thrash).
__global__ __launch_bounds__(256, 2) void k_gemm3(
    const unsigned short* __restrict__ A,
    const unsigned short* __restrict__ W3,   // [3072][1024] = Wq;Wk;Wv rows
    const float* __restrict__ bq, const float* __restrict__ bk,
    const float* __restrict__ bv,
    unsigned short* __restrict__ Qo,   // [64][2048][64]
    unsigned short* __restrict__ Ko,   // [64][2048][64]
    unsigned short* __restrict__ Vto,  // [64][64][2048]
    float cexp) {
  const int K = HID;
  __shared__ __align__(16) unsigned short sA[128 * 64];
  __shared__ __align__(16) unsigned short sB[128 * 64];
  // XCD partition: nwg = 64*24 = 1536, 192/XCD
  const int orig = blockIdx.x + gridDim.x * blockIdx.y;
  const int xcd = orig & 7, idx = orig >> 3;      // idx in [0,192)
  const int gm = xcd & 3, gn = xcd >> 1 >> 1;     // 4 m-groups x 2 n-groups
  const int m0 = (gm * 16 + (idx & 15)) * 128;    // 64 m-panels
  const int n0 = (gn * 12 + (idx >> 4)) * 128;    // 24 n-panels
  const int tid = threadIdx.x;
  const int lane = tid & 63, wid = tid >> 6;
  const int wr = wid >> 1, wc = wid & 1;
  const int lr = lane & 15, lg = lane >> 4;

  f32x4 acc[4][4] = {};

  const unsigned short* gA = A + (size_t)m0 * K;
  const unsigned short* gW = W3 + (size_t)n0 * K;

  for (int kt = 0; kt < K; kt += 64) {
#pragma unroll
    for (int i = 0; i < 4; ++i) {
      int c = tid + i * 256;
      int row = c >> 3, col = (c & 7) << 3;
      GLDS(gA + (size_t)row * K + kt + col, (char*)sA + (size_t)c * 16);
      GLDS(gW + (size_t)row * K + kt + col, (char*)sB + (size_t)c * 16);
    }
    __syncthreads();
#pragma unroll
    for (int kk = 0; kk < 64; kk += 32) {
      bf16x8 a[4], b[4];
      const int co = kk + lg * 8;
#pragma unroll
      for (int m = 0; m < 4; ++m)
        a[m] = *reinterpret_cast<const bf16x8*>(sA + (wr * 64 + m * 16 + lr) * 64 + co);
#pragma unroll
      for (int n = 0; n < 4; ++n)
        b[n] = *reinterpret_cast<const bf16x8*>(sB + (wc * 64 + n * 16 + lr) * 64 + co);
      __builtin_amdgcn_s_setprio(1);
#pragma unroll
      for (int m = 0; m < 4; ++m)
#pragma unroll
        for (int n = 0; n < 4; ++n)
          acc[m][n] = mfma16(a[m], b[n], acc[m][n]);
      __builtin_amdgcn_s_setprio(0);
    }
    __syncthreads();
  }

  const int sect = n0 >> 10; // 0=Q 1=K 2=V
  const float* bias = (sect == 0) ? bq : (sect == 1) ? bk : bv;
  const float sc = (sect == 0) ? cexp : 1.0f;

  if (sect < 2) {
    unsigned short* C = (sect == 0) ? Qo : Ko;
#pragma unroll
    for (int m = 0; m < 4; ++m) {
      int row0 = m0 + wr * 64 + m * 16 + lg * 4;
      int b = row0 >> 11;
#pragma unroll
      for (int n = 0; n < 4; ++n) {
        int colq = (n0 + wc * 64 + n * 16 + lr) & 1023;
        float bvv = bias[colq];
        int h = colq >> 6, d = colq & 63;
        size_t base = ((size_t)(b * NH + h) * SEQ) * HD + d;
#pragma unroll
        for (int r = 0; r < 4; ++r) {
          int tok = (row0 + r) & 2047;
          C[base + (size_t)tok * HD] = f2bf((acc[m][n][r] + bvv) * sc);
        }
      }
    }
  } else {
#pragma unroll
    for (int m = 0; m < 4; ++m) {
      int row0 = m0 + wr * 64 + m * 16 + lg * 4;
      int b = row0 >> 11;
      int tok0 = row0 & 2047;
#pragma unroll
      for (int n = 0; n < 4; ++n) {
        int colq = (n0 + wc * 64 + n * 16 + lr) & 1023;
        float bvv = bias[colq];
        int h = colq >> 6, d = colq & 63;
        ushort4 pk;
        pk.x = f2bf(acc[m][n][0] + bvv);
        pk.y = f2bf(acc[m][n][1] + bvv);
        pk.z = f2bf(acc[m][n][2] + bvv);
        pk.w = f2bf(acc[m][n][3] + bvv);
        *reinterpret_cast<ushort4*>(&Vto[((size_t)(b * NH + h) * HD + d) * SEQ + tok0]) = pk;
      }
    }
  }
}

// ---------------- out-proj GEMM: fp32 out = O @ Wo^T + bo ----------------
__global__ __launch_bounds__(256, 2) void k_gemmo(
    const unsigned short* __restrict__ A,
    const unsigned short* __restrict__ W,
    const float* __restrict__ bias,
    float* __restrict__ C) {
  const int K = HID;
  __shared__ __align__(16) unsigned short sA[128 * 64];
  __shared__ __align__(16) unsigned short sB[128 * 64];
  // XCD partition: nwg = 64*8 = 512, 64/XCD (4 m-groups x 2 n-groups)
  const int orig = blockIdx.x + gridDim.x * blockIdx.y;
  const int xcd = orig & 7, idx = orig >> 3;      // idx in [0,64)
  const int gm = xcd & 3, gn = xcd >> 2;
  const int m0 = (gm * 16 + (idx & 15)) * 128;
  const int n0 = (gn * 4 + (idx >> 4)) * 128;
  const int tid = threadIdx.x;
  const int lane = tid & 63, wid = tid >> 6;
  const int wr = wid >> 1, wc = wid & 1;
  const int lr = lane & 15, lg = lane >> 4;

  f32x4 acc[4][4] = {};

  const unsigned short* gA = A + (size_t)m0 * K;
  const unsigned short* gW = W + (size_t)n0 * K;

  for (int kt = 0; kt < K; kt += 64) {
#pragma unroll
    for (int i = 0; i < 4; ++i) {
      int c = tid + i * 256;
      int row = c >> 3, col = (c & 7) << 3;
      GLDS(gA + (size_t)row * K + kt + col, (char*)sA + (size_t)c * 16);
      GLDS(gW + (size_t)row * K + kt + col, (char*)sB + (size_t)c * 16);
    }
    __syncthreads();
#pragma unroll
    for (int kk = 0; kk < 64; kk += 32) {
      bf16x8 a[4], b[4];
      const int co = kk + lg * 8;
#pragma unroll
      for (int m = 0; m < 4; ++m)
        a[m] = *reinterpret_cast<const bf16x8*>(sA + (wr * 64 + m * 16 + lr) * 64 + co);
#pragma unroll
      for (int n = 0; n < 4; ++n)
        b[n] = *reinterpret_cast<const bf16x8*>(sB + (wc * 64 + n * 16 + lr) * 64 + co);
      __builtin_amdgcn_s_setprio(1);
#pragma unroll
      for (int m = 0; m < 4; ++m)
#pragma unroll
        for (int n = 0; n < 4; ++n)
          acc[m][n] = mfma16(a[m], b[n], acc[m][n]);
      __builtin_amdgcn_s_setprio(0);
    }
    __syncthreads();
  }

#pragma unroll
  for (int m = 0; m < 4; ++m) {
    int row0 = m0 + wr * 64 + m * 16 + lg * 4;
#pragma unroll
    for (int n = 0; n < 4; ++n) {
      int col = n0 + wc * 64 + n * 16 + lr;
      float bvv = bias[col];
#pragma unroll
      for (int r = 0; r < 4; ++r)
        C[(size_t)(row0 + r) * HID + col] = acc[m][n][r] + bvv;
    }
  }
}

// ---------------- attention (r5 structure + MFMA den) ----------------
// grid (bh=64, qt=16); 4 waves; wave owns 32 q-rows. KVB=64, single buffer,
// in-loop global_load_lds staging (pre-swizzled source), 2 barriers/tile.
// S^T = mfma(K,Q): lane holds P[q=w*32+m*16+lr][kv=n*16+4lg+r] -> exp2,
// cvt_pk pairs, swizzled b64 write to sP (wave-private rows -> no barrier
// between P-write and PV-read). den: accd[m] += mfma(pa[m], ones).
#define KVB 64

__global__ __launch_bounds__(256, 4) void k_attn(
    const unsigned short* __restrict__ Qg,  // [64][2048][64]
    const unsigned short* __restrict__ Kg,  // [64][2048][64]
    const unsigned short* __restrict__ Vt,  // [64][64][2048]
    unsigned short* __restrict__ Og) {      // [8192][1024] bf16
  __shared__ __align__(16) unsigned short sP[128 * 64]; // 16KB (Q staged here first)
  __shared__ __align__(16) unsigned short sK[KVB * 64]; //  8KB
  __shared__ __align__(16) unsigned short sV[KVB * 64]; //  8KB

  const int bh = blockIdx.x;
  const int qt = blockIdx.y;
  const int tid = threadIdx.x;
  const int lane = tid & 63, wid = tid >> 6;
  const int lr = lane & 15, lg = lane >> 4;

  const unsigned short* Qh = Qg + ((size_t)bh * SEQ + (size_t)qt * 128) * HD;
  const unsigned short* Kh = Kg + (size_t)bh * SEQ * HD;
  const unsigned short* Vh = Vt + (size_t)bh * HD * SEQ;

  // staging geometry: thread covers chunks c0=tid (row r0), c1=tid+256 (row r0+32)
  const int r0 = tid >> 3, r1 = r0 + 32;
  const int cb0 = SWZ(r0, (tid & 7) << 4) >> 1; // pre-swizzled source short-offset
  const int cb1 = SWZ(r1, (tid & 7) << 4) >> 1;

  // stage Q tile (128 rows x 128B): linear dest byte c*16, source pre-swizzled
#pragma unroll
  for (int i = 0; i < 4; ++i) {
    int c = tid + i * 256;
    int row = c >> 3;
    int cbl = SWZ(row, (c & 7) << 4);
    GLDS(Qh + (size_t)row * HD + (cbl >> 1), (char*)sP + (size_t)c * 16);
  }
  __syncthreads();
  bf16x8 qb[2][2];
#pragma unroll
  for (int m = 0; m < 2; ++m)
#pragma unroll
    for (int kd = 0; kd < 2; ++kd) {
      int row = wid * 32 + m * 16 + lr;
      qb[m][kd] = *reinterpret_cast<const bf16x8*>(
          (const char*)sP + row * 128 + SWZ(lr, kd * 64 + lg * 16));
    }
  // safe: qb reads precede this thread's arrival at the first in-loop barrier;
  // sP is only rewritten (P-phase) after that barrier.

  const unsigned short onev = (unsigned short)0x3F80; // bf16 1.0
  const bf16x8 ones = {(short)onev, (short)onev, (short)onev, (short)onev,
                       (short)onev, (short)onev, (short)onev, (short)onev};

  f32x4 acco[2][4] = {};
  f32x4 accd[2] = {};

  for (int kt = 0; kt < SEQ; kt += KVB) {
    // stage K [64 kv][64 d] and V [64 d][64 kv] (pre-swizzled source)
    GLDS(Kh + (size_t)(kt + r0) * HD + cb0, (char*)sK + (size_t)tid * 16);
    GLDS(Kh + (size_t)(kt + r1) * HD + cb1, (char*)sK + (size_t)(tid + 256) * 16);
    GLDS(Vh + (size_t)r0 * SEQ + kt + cb0, (char*)sV + (size_t)tid * 16);
    GLDS(Vh + (size_t)r1 * SEQ + kt + cb1, (char*)sV + (size_t)(tid + 256) * 16);
    __syncthreads(); // staged tiles visible (vmcnt drained)

    // S^T = K Q^T : accs[m][n]: kv = n*16+4lg+r, q = wid*32+m*16+lr
    f32x4 accs[2][4] = {};
#pragma unroll
    for (int kd = 0; kd < 2; ++kd) {
      bf16x8 ka[4];
#pragma unroll
      for (int n = 0; n < 4; ++n)
        ka[n] = *reinterpret_cast<const bf16x8*>(
            (const char*)sK + (n * 16 + lr) * 128 + SWZ(lr, kd * 64 + lg * 16));
      __builtin_amdgcn_s_setprio(1);
#pragma unroll
      for (int n = 0; n < 4; ++n) {
        accs[0][n] = mfma16(ka[n], qb[0][kd], accs[0][n]);
        accs[1][n] = mfma16(ka[n], qb[1][kd], accs[1][n]);
      }
      __builtin_amdgcn_s_setprio(0);
    }

    // P = exp2(S^T) -> packed bf16 swizzled b64 write to sP[q][kv] (own rows)
#pragma unroll
    for (int m = 0; m < 2; ++m) {
      const int q = wid * 32 + m * 16 + lr;
#pragma unroll
      for (int n = 0; n < 4; ++n) {
        float p0 = exp2f(accs[m][n][0]);
        float p1 = exp2f(accs[m][n][1]);
        float p2 = exp2f(accs[m][n][2]);
        float p3 = exp2f(accs[m][n][3]);
        unsigned w0, w1;
        asm("v_cvt_pk_bf16_f32 %0, %1, %2" : "=v"(w0) : "v"(p0), "v"(p1));
        asm("v_cvt_pk_bf16_f32 %0, %1, %2" : "=v"(w1) : "v"(p2), "v"(p3));
        uint2 pk; pk.x = w0; pk.y = w1;
        *reinterpret_cast<uint2*>((char*)sP + q * 128 + SWZ(q, n * 32 + lg * 8)) = pk;
      }
    }
    // no barrier: PV below reads only this wave's own sP rows.

    // O += P V ; den += P * ones
#pragma unroll
    for (int js = 0; js < 2; ++js) {
      bf16x8 pa[2], vb[4];
#pragma unroll
      for (int m = 0; m < 2; ++m) {
        int row = wid * 32 + m * 16 + lr;
        pa[m] = *reinterpret_cast<const bf16x8*>(
            (const char*)sP + row * 128 + SWZ(lr, js * 64 + lg * 16));
      }
#pragma unroll
      for (int n = 0; n < 4; ++n)
        vb[n] = *reinterpret_cast<const bf16x8*>(
            (const char*)sV + (n * 16 + lr) * 128 + SWZ(lr, js * 64 + lg * 16));
      __builtin_amdgcn_s_setprio(1);
#pragma unroll
      for (int m = 0; m < 2; ++m) {
#pragma unroll
        for (int n = 0; n < 4; ++n)
          acco[m][n] = mfma16(pa[m], vb[n], acco[m][n]);
        accd[m] = mfma16(pa[m], ones, accd[m]);
      }
      __builtin_amdgcn_s_setprio(0);
    }
    __syncthreads(); // protect sK/sV/sP before next staging
  }

  // rden directly from accd (identical fragment layout to acco)
  const int b = bh >> 4, h = bh & 15;
#pragma unroll
  for (int m = 0; m < 2; ++m) {
    int tok0 = qt * 128 + wid * 32 + m * 16 + lg * 4;
#pragma unroll
    for (int r = 0; r < 4; ++r) {
      float rd = 1.0f / accd[m][r];
#pragma unroll
      for (int n = 0; n < 4; ++n) {
        int col = h * 64 + n * 16 + lr;
        Og[(size_t)(b * SEQ + tok0 + r) * HID + col] = f2bf(acco[m][n][r] * rd);
      }
    }
  }
}

// ---------------- launch ----------------
extern "C" void kernel_launch(void* const* d_in, const int* in_sizes, int n_in,
                              void* d_out, int out_size, void* d_ws, size_t ws_size,
                              hipStream_t stream) {
  (void)in_sizes; (void)n_in; (void)out_size; (void)ws_size;
  const float* x = (const float*)d_in[0];
  const float* Wq = (const float*)d_in[1];
  const float* bq = (const float*)d_in[2];
  const float* Wk = (const float*)d_in[3];
  const float* bk = (const float*)d_in[4];
  const float* Wv = (const float*)d_in[5];
  const float* bv = (const float*)d_in[6];
  const float* Wo = (const float*)d_in[7];
  const float* bo = (const float*)d_in[8];

  unsigned short* ws = (unsigned short*)d_ws;
  unsigned short* xb = ws;
  unsigned short* wqb = xb + (size_t)MTOT * HID;  // Wq;Wk;Wv;Wo contiguous
  unsigned short* wob = wqb + 3 * (size_t)HID * HID;
  unsigned short* qb = wob + (size_t)HID * HID;   // [64][2048][64]
  unsigned short* kb = qb + (size_t)MTOT * HID;   // [64][2048][64]
  unsigned short* vtb = kb + (size_t)MTOT * HID;  // [64][64][2048]
  unsigned short* ob = vtb + (size_t)MTOT * HID;  // [8192][1024]

  const float cexp = 0.04508422f; // log2(e)/32

  k_cvt_all<<<(MTOT * HID / 4 + 4 * (HID * HID / 4)) / 256, 256, 0, stream>>>(
      x, Wq, Wk, Wv, Wo, ws);

  k_gemm3<<<dim3(64, 24), 256, 0, stream>>>(
      xb, wqb, bq, bk, bv, qb, kb, vtb, cexp);

  k_attn<<<dim3(64, SEQ / 128), 256, 0, stream>>>(qb, kb, vtb, ob);

  k_gemmo<<<dim3(64, 8), 256, 0, stream>>>(ob, wob, bo, (float*)d_out);
}

// Round 10
// 211.697 us; speedup vs baseline: 1.2536x; 1.0011x over previous
//
#include <hip/hip_runtime.h>
#include <stdint.h>

// MultiHeadAttention: x[4,2048,1024] fp32; Wq/Wk/Wv/Wo [1024,1024]; biases zero.
// out = softmax((xWq^T)(xWk^T)^T / 32) (xWv^T) Wo^T + bo   (16 heads, d=64)
//
// Pipeline (bf16 MFMA, fp32 accum):
//  k_cvt_all: x,W* fp32->bf16 (single fused launch)
//  k_gemm3: fused QKV projection, N=3072, XCD-partitioned grid (r8)
//  k_attn:  32x32x16 MFMA flash attention, fully in-register softmax.
//           Swapped S^T -> lane-local P row -> pa = cvt_pk in NATIVE register
//           order (no cross-lane ops); the kv permutation is absorbed into
//           the V-side LDS read (two b64 chunks per frag at kv = base+4*hi
//           and base+8+4*hi). r9's permlane32_swap pairing was wrong ->
//           removed entirely. den via mfma(P, ones) (acco's exact layout).
//           16KB LDS, KVB=64, 2 barriers/tile. launch_bounds(256,4).
//  k_gemmo: O @ Wo^T + bo -> fp32 d_out, XCD-partitioned grid (r8)

#define HID 1024
#define NH 16
#define HD 64
#define BB 4
#define SEQ 2048
#define MTOT (BB * SEQ) // 8192

typedef short bf16x8 __attribute__((ext_vector_type(8)));
typedef float f32x4 __attribute__((ext_vector_type(4)));
typedef float f32x16 __attribute__((ext_vector_type(16)));

// swizzle: byte col within a 128B row, XORed by row&7 (16B granular)
#define SWZ(row, cb) ((cb) ^ (((row) & 7) << 4))

#define GLDS(gp, lp) __builtin_amdgcn_global_load_lds( \
    (const __attribute__((address_space(1))) void*)(gp), \
    (__attribute__((address_space(3))) void*)(lp), 16, 0, 0)

static __device__ __forceinline__ unsigned short f2bf(float f) {
  unsigned u = __float_as_uint(f);
  u += 0x7fffu + ((u >> 16) & 1u); // RNE
  return (unsigned short)(u >> 16);
}

static __device__ __forceinline__ f32x4 mfma16(bf16x8 a, bf16x8 b, f32x4 c) {
  return __builtin_amdgcn_mfma_f32_16x16x32_bf16(a, b, c, 0, 0, 0);
}
static __device__ __forceinline__ f32x16 mfma32(bf16x8 a, bf16x8 b, f32x16 c) {
  return __builtin_amdgcn_mfma_f32_32x32x16_bf16(a, b, c, 0, 0, 0);
}

// ---------------- fp32 -> bf16 convert, all tensors, one launch ----------------
__global__ void k_cvt_all(const float* __restrict__ x,
                          const float* __restrict__ Wq, const float* __restrict__ Wk,
                          const float* __restrict__ Wv, const float* __restrict__ Wo,
                          unsigned short* __restrict__ ws) {
  const int X4 = MTOT * HID / 4;
  const int W4 = HID * HID / 4;
  int i = blockIdx.x * blockDim.x + threadIdx.x;
  const float* src;
  unsigned short* dst;
  int off;
  if (i < X4) {
    src = x; dst = ws; off = i;
  } else {
    int j = i - X4;
    int w = j / W4;
    off = j - w * W4;
    src = (w == 0) ? Wq : (w == 1) ? Wk : (w == 2) ? Wv : Wo;
    dst = ws + (size_t)MTOT * HID + (size_t)w * HID * HID;
  }
  float4 v = reinterpret_cast<const float4*>(src)[off];
  ushort4 o;
  o.x = f2bf(v.x); o.y = f2bf(v.y); o.z = f2bf(v.z); o.w = f2bf(v.w);
  reinterpret_cast<ushort4*>(dst)[off] = o;
}

// ---------------- fused QKV GEMM: [8192,3072] = A[M,K] @ W3[3N,K]^T ----------------
__global__ __launch_bounds__(256, 2) void k_gemm3(
    const unsigned short* __restrict__ A,
    const unsigned short* __restrict__ W3,
    const float* __restrict__ bq, const float* __restrict__ bk,
    const float* __restrict__ bv,
    unsigned short* __restrict__ Qo,   // [64][2048][64]
    unsigned short* __restrict__ Ko,   // [64][2048][64]
    unsigned short* __restrict__ Vto,  // [64][64][2048]
    float cexp) {
  const int K = HID;
  __shared__ __align__(16) unsigned short sA[128 * 64];
  __shared__ __align__(16) unsigned short sB[128 * 64];
  const int orig = blockIdx.x + gridDim.x * blockIdx.y;
  const int xcd = orig & 7, idx = orig >> 3;
  const int gm = xcd & 3, gn = xcd >> 1 >> 1;
  const int m0 = (gm * 16 + (idx & 15)) * 128;
  const int n0 = (gn * 12 + (idx >> 4)) * 128;
  const int tid = threadIdx.x;
  const int lane = tid & 63, wid = tid >> 6;
  const int wr = wid >> 1, wc = wid & 1;
  const int lr = lane & 15, lg = lane >> 4;

  f32x4 acc[4][4] = {};

  const unsigned short* gA = A + (size_t)m0 * K;
  const unsigned short* gW = W3 + (size_t)n0 * K;

  for (int kt = 0; kt < K; kt += 64) {
#pragma unroll
    for (int i = 0; i < 4; ++i) {
      int c = tid + i * 256;
      int row = c >> 3, col = (c & 7) << 3;
      GLDS(gA + (size_t)row * K + kt + col, (char*)sA + (size_t)c * 16);
      GLDS(gW + (size_t)row * K + kt + col, (char*)sB + (size_t)c * 16);
    }
    __syncthreads();
#pragma unroll
    for (int kk = 0; kk < 64; kk += 32) {
      bf16x8 a[4], b[4];
      const int co = kk + lg * 8;
#pragma unroll
      for (int m = 0; m < 4; ++m)
        a[m] = *reinterpret_cast<const bf16x8*>(sA + (wr * 64 + m * 16 + lr) * 64 + co);
#pragma unroll
      for (int n = 0; n < 4; ++n)
        b[n] = *reinterpret_cast<const bf16x8*>(sB + (wc * 64 + n * 16 + lr) * 64 + co);
      __builtin_amdgcn_s_setprio(1);
#pragma unroll
      for (int m = 0; m < 4; ++m)
#pragma unroll
        for (int n = 0; n < 4; ++n)
          acc[m][n] = mfma16(a[m], b[n], acc[m][n]);
      __builtin_amdgcn_s_setprio(0);
    }
    __syncthreads();
  }

  const int sect = n0 >> 10; // 0=Q 1=K 2=V
  const float* bias = (sect == 0) ? bq : (sect == 1) ? bk : bv;
  const float sc = (sect == 0) ? cexp : 1.0f;

  if (sect < 2) {
    unsigned short* C = (sect == 0) ? Qo : Ko;
#pragma unroll
    for (int m = 0; m < 4; ++m) {
      int row0 = m0 + wr * 64 + m * 16 + lg * 4;
      int b = row0 >> 11;
#pragma unroll
      for (int n = 0; n < 4; ++n) {
        int colq = (n0 + wc * 64 + n * 16 + lr) & 1023;
        float bvv = bias[colq];
        int h = colq >> 6, d = colq & 63;
        size_t base = ((size_t)(b * NH + h) * SEQ) * HD + d;
#pragma unroll
        for (int r = 0; r < 4; ++r) {
          int tok = (row0 + r) & 2047;
          C[base + (size_t)tok * HD] = f2bf((acc[m][n][r] + bvv) * sc);
        }
      }
    }
  } else {
#pragma unroll
    for (int m = 0; m < 4; ++m) {
      int row0 = m0 + wr * 64 + m * 16 + lg * 4;
      int b = row0 >> 11;
      int tok0 = row0 & 2047;
#pragma unroll
      for (int n = 0; n < 4; ++n) {
        int colq = (n0 + wc * 64 + n * 16 + lr) & 1023;
        float bvv = bias[colq];
        int h = colq >> 6, d = colq & 63;
        ushort4 pk;
        pk.x = f2bf(acc[m][n][0] + bvv);
        pk.y = f2bf(acc[m][n][1] + bvv);
        pk.z = f2bf(acc[m][n][2] + bvv);
        pk.w = f2bf(acc[m][n][3] + bvv);
        *reinterpret_cast<ushort4*>(&Vto[((size_t)(b * NH + h) * HD + d) * SEQ + tok0]) = pk;
      }
    }
  }
}

// ---------------- out-proj GEMM: fp32 out = O @ Wo^T + bo ----------------
__global__ __launch_bounds__(256, 2) void k_gemmo(
    const unsigned short* __restrict__ A,
    const unsigned short* __restrict__ W,
    const float* __restrict__ bias,
    float* __restrict__ C) {
  const int K = HID;
  __shared__ __align__(16) unsigned short sA[128 * 64];
  __shared__ __align__(16) unsigned short sB[128 * 64];
  const int orig = blockIdx.x + gridDim.x * blockIdx.y;
  const int xcd = orig & 7, idx = orig >> 3;
  const int gm = xcd & 3, gn = xcd >> 2;
  const int m0 = (gm * 16 + (idx & 15)) * 128;
  const int n0 = (gn * 4 + (idx >> 4)) * 128;
  const int tid = threadIdx.x;
  const int lane = tid & 63, wid = tid >> 6;
  const int wr = wid >> 1, wc = wid & 1;
  const int lr = lane & 15, lg = lane >> 4;

  f32x4 acc[4][4] = {};

  const unsigned short* gA = A + (size_t)m0 * K;
  const unsigned short* gW = W + (size_t)n0 * K;

  for (int kt = 0; kt < K; kt += 64) {
#pragma unroll
    for (int i = 0; i < 4; ++i) {
      int c = tid + i * 256;
      int row = c >> 3, col = (c & 7) << 3;
      GLDS(gA + (size_t)row * K + kt + col, (char*)sA + (size_t)c * 16);
      GLDS(gW + (size_t)row * K + kt + col, (char*)sB + (size_t)c * 16);
    }
    __syncthreads();
#pragma unroll
    for (int kk = 0; kk < 64; kk += 32) {
      bf16x8 a[4], b[4];
      const int co = kk + lg * 8;
#pragma unroll
      for (int m = 0; m < 4; ++m)
        a[m] = *reinterpret_cast<const bf16x8*>(sA + (wr * 64 + m * 16 + lr) * 64 + co);
#pragma unroll
      for (int n = 0; n < 4; ++n)
        b[n] = *reinterpret_cast<const bf16x8*>(sB + (wc * 64 + n * 16 + lr) * 64 + co);
      __builtin_amdgcn_s_setprio(1);
#pragma unroll
      for (int m = 0; m < 4; ++m)
#pragma unroll
        for (int n = 0; n < 4; ++n)
          acc[m][n] = mfma16(a[m], b[n], acc[m][n]);
      __builtin_amdgcn_s_setprio(0);
    }
    __syncthreads();
  }

#pragma unroll
  for (int m = 0; m < 4; ++m) {
    int row0 = m0 + wr * 64 + m * 16 + lg * 4;
#pragma unroll
    for (int n = 0; n < 4; ++n) {
      int col = n0 + wc * 64 + n * 16 + lr;
      float bvv = bias[col];
#pragma unroll
      for (int r = 0; r < 4; ++r)
        C[(size_t)(row0 + r) * HID + col] = acc[m][n][r] + bvv;
    }
  }
}

// ---------------- attention: 32x32 MFMA, in-register softmax ----------------
// grid (bh=64, qt=16); 4 waves; wave owns 32 q-rows (band wid*32..+31).
// Per 64-kv tile:
//  S^T: accs[nblk] = sum_ks mfma32(K_frag[nblk,ks], Q_frag[ks])
//       lane(q=l31,hi): kv = nblk*32 + (reg&3)+8*(reg>>2)+4*hi
//  P:   exp2 (Q pre-scaled) -> pa[i] = cvt_pk of p[g*8..g*8+7] in NATIVE
//       order (i = nblk*2+g). The implied k->kv map of MFMA instance i is
//       kv(i, k=8hi+j) = i*16 + (j&3) + 8*(j>>2) + 4*hi — injective, so we
//       match it on the V side instead of permuting P across lanes.
//  PV:  B-frag for instance i, lane(d=dblk*32+l31, hi): V[kv(i,8hi+j)][d]
//       = sV[d] shorts {i*16+4hi..+3} and {i*16+8+4hi..+3}: two b64 reads.
//       acco[dblk] += mfma32(pa[i], vb[dblk]); accd += mfma32(pa[i], ones).
// LDS 16KB: sK=[64 kv][128B] | sV=[64 d][128B] (V^T). Q staged first, hoisted.
#define KVB 64

__global__ __launch_bounds__(256, 4) void k_attn(
    const unsigned short* __restrict__ Qg,  // [64][2048][64]
    const unsigned short* __restrict__ Kg,  // [64][2048][64]
    const unsigned short* __restrict__ Vt,  // [64][64][2048]
    unsigned short* __restrict__ Og) {      // [8192][1024] bf16
  __shared__ __align__(16) unsigned short smem[128 * 64]; // 16KB

  const int bh = blockIdx.x;
  const int qt = blockIdx.y;
  const int tid = threadIdx.x;
  const int lane = tid & 63, wid = tid >> 6;
  const int l31 = lane & 31, hi = lane >> 5;

  const unsigned short* Qh = Qg + ((size_t)bh * SEQ + (size_t)qt * 128) * HD;
  const unsigned short* Kh = Kg + (size_t)bh * SEQ * HD;
  const unsigned short* Vh = Vt + (size_t)bh * HD * SEQ;

  char* sK = (char*)smem;           // [64 kv][128B]
  char* sV = (char*)smem + 8192;    // [64 d ][128B]

  // staging geometry: chunks c0=tid (row r0 in 0..31), c1=tid+256 (row r0+32)
  const int r0 = tid >> 3, r1 = r0 + 32;
  const int cb0 = SWZ(r0, (tid & 7) << 4) >> 1; // pre-swizzled source short-offset
  const int cb1 = SWZ(r1, (tid & 7) << 4) >> 1;

  // stage Q tile (128 rows x 128B) across whole smem, source pre-swizzled
#pragma unroll
  for (int i = 0; i < 4; ++i) {
    int c = tid + i * 256;
    int row = c >> 3;
    int cbl = SWZ(row, (c & 7) << 4);
    GLDS(Qh + (size_t)row * HD + (cbl >> 1), (char*)smem + (size_t)c * 16);
  }
  __syncthreads();
  // Q B-frags: col q = l31 (wave band), k(d) = ks*16 + hi*8 + j
  bf16x8 qb[4];
  {
    int row = wid * 32 + l31;
#pragma unroll
    for (int ks = 0; ks < 4; ++ks)
      qb[ks] = *reinterpret_cast<const bf16x8*>(
          (const char*)smem + row * 128 + SWZ(row, ks * 32 + hi * 16));
  }
  __syncthreads(); // all waves read Q before smem is overwritten by K/V

  const unsigned short onev = (unsigned short)0x3F80; // bf16 1.0
  const bf16x8 ones = {(short)onev, (short)onev, (short)onev, (short)onev,
                       (short)onev, (short)onev, (short)onev, (short)onev};

  f32x16 acco[2] = {};  // O: col d = dblk*32+l31, row q = crow(reg,hi)
  f32x16 accd = {};     // den, same layout

  for (int kt = 0; kt < SEQ; kt += KVB) {
    // stage K [64 kv][64 d] and V^T [64 d][64 kv] (pre-swizzled source)
    GLDS(Kh + (size_t)(kt + r0) * HD + cb0, sK + (size_t)tid * 16);
    GLDS(Kh + (size_t)(kt + r1) * HD + cb1, sK + (size_t)(tid + 256) * 16);
    GLDS(Vh + (size_t)r0 * SEQ + kt + cb0, sV + (size_t)tid * 16);
    GLDS(Vh + (size_t)r1 * SEQ + kt + cb1, sV + (size_t)(tid + 256) * 16);
    __syncthreads(); // staged tiles visible (vmcnt drained)

    // S^T: accs[nblk], kv = nblk*32 + crow(reg,hi), q = l31
    f32x16 accs[2] = {};
#pragma unroll
    for (int ks = 0; ks < 4; ++ks) {
      bf16x8 ka0 = *reinterpret_cast<const bf16x8*>(
          sK + (0 + l31) * 128 + SWZ(l31, ks * 32 + hi * 16));
      bf16x8 ka1 = *reinterpret_cast<const bf16x8*>(
          sK + (32 + l31) * 128 + SWZ(32 + l31, ks * 32 + hi * 16));
      __builtin_amdgcn_s_setprio(1);
      accs[0] = mfma32(ka0, qb[ks], accs[0]);
      accs[1] = mfma32(ka1, qb[ks], accs[1]);
      __builtin_amdgcn_s_setprio(0);
    }

    // P = exp2(S^T) in regs -> pa[i] in NATIVE lane order (no cross-lane ops)
    bf16x8 pa[4];
#pragma unroll
    for (int nblk = 0; nblk < 2; ++nblk) {
      float p[16];
#pragma unroll
      for (int r = 0; r < 16; ++r) p[r] = exp2f(accs[nblk][r]);
#pragma unroll
      for (int g = 0; g < 2; ++g) {
        const int bs = g * 8;
        unsigned w0, w1, w2, w3;
        asm("v_cvt_pk_bf16_f32 %0, %1, %2" : "=v"(w0) : "v"(p[bs + 0]), "v"(p[bs + 1]));
        asm("v_cvt_pk_bf16_f32 %0, %1, %2" : "=v"(w1) : "v"(p[bs + 2]), "v"(p[bs + 3]));
        asm("v_cvt_pk_bf16_f32 %0, %1, %2" : "=v"(w2) : "v"(p[bs + 4]), "v"(p[bs + 5]));
        asm("v_cvt_pk_bf16_f32 %0, %1, %2" : "=v"(w3) : "v"(p[bs + 6]), "v"(p[bs + 7]));
        uint4 pk4; pk4.x = w0; pk4.y = w1; pk4.z = w2; pk4.w = w3;
        pa[nblk * 2 + g] = *reinterpret_cast<bf16x8*>(&pk4);
      }
    }

    // PV: O += P V ; den += P * ones. Instance i covers kv window i*16..+15
    // with map kv = i*16 + (j&3)+8*(j>>2)+4hi -> V reads split into 2x b64.
#pragma unroll
    for (int i = 0; i < 4; ++i) {
      const int bb = i * 32 + hi * 8; // byte base within a 128B sV row
      bf16x8 vb[2];
#pragma unroll
      for (int dblk = 0; dblk < 2; ++dblk) {
        const int rsw = dblk * 32 + l31;
        const char* rowp = sV + rsw * 128;
        uint2 lo = *reinterpret_cast<const uint2*>(rowp + SWZ(rsw, bb));
        uint2 hi2 = *reinterpret_cast<const uint2*>(rowp + SWZ(rsw, bb + 16));
        uint4 q4; q4.x = lo.x; q4.y = lo.y; q4.z = hi2.x; q4.w = hi2.y;
        vb[dblk] = *reinterpret_cast<bf16x8*>(&q4);
      }
      __builtin_amdgcn_s_setprio(1);
      acco[0] = mfma32(pa[i], vb[0], acco[0]);
      acco[1] = mfma32(pa[i], vb[1], acco[1]);
      accd = mfma32(pa[i], ones, accd);
      __builtin_amdgcn_s_setprio(0);
    }
    __syncthreads(); // protect sK/sV before next staging
  }

  // epilogue: O[q][d] = acco/accd; q = crow(reg,hi), d = dblk*32 + l31
  const int b = bh >> 4, h = bh & 15;
#pragma unroll
  for (int reg = 0; reg < 16; ++reg) {
    int q = (reg & 3) + 8 * (reg >> 2) + 4 * hi;
    int tok = qt * 128 + wid * 32 + q;
    float rd = 1.0f / accd[reg];
    size_t rowoff = (size_t)(b * SEQ + tok) * HID + h * 64;
    Og[rowoff + l31] = f2bf(acco[0][reg] * rd);
    Og[rowoff + 32 + l31] = f2bf(acco[1][reg] * rd);
  }
}

// ---------------- launch ----------------
extern "C" void kernel_launch(void* const* d_in, const int* in_sizes, int n_in,
                              void* d_out, int out_size, void* d_ws, size_t ws_size,
                              hipStream_t stream) {
  (void)in_sizes; (void)n_in; (void)out_size; (void)ws_size;
  const float* x = (const float*)d_in[0];
  const float* Wq = (const float*)d_in[1];
  const float* bq = (const float*)d_in[2];
  const float* Wk = (const float*)d_in[3];
  const float* bk = (const float*)d_in[4];
  const float* Wv = (const float*)d_in[5];
  const float* bv = (const float*)d_in[6];
  const float* Wo = (const float*)d_in[7];
  const float* bo = (const float*)d_in[8];

  unsigned short* ws = (unsigned short*)d_ws;
  unsigned short* xb = ws;
  unsigned short* wqb = xb + (size_t)MTOT * HID;  // Wq;Wk;Wv;Wo contiguous
  unsigned short* wob = wqb + 3 * (size_t)HID * HID;
  unsigned short* qb = wob + (size_t)HID * HID;   // [64][2048][64]
  unsigned short* kb = qb + (size_t)MTOT * HID;   // [64][2048][64]
  unsigned short* vtb = kb + (size_t)MTOT * HID;  // [64][64][2048]
  unsigned short* ob = vtb + (size_t)MTOT * HID;  // [8192][1024]

  const float cexp = 0.04508422f; // log2(e)/32

  k_cvt_all<<<(MTOT * HID / 4 + 4 * (HID * HID / 4)) / 256, 256, 0, stream>>>(
      x, Wq, Wk, Wv, Wo, ws);

  k_gemm3<<<dim3(64, 24), 256, 0, stream>>>(
      xb, wqb, bq, bk, bv, qb, kb, vtb, cexp);

  k_attn<<<dim3(64, SEQ / 128), 256, 0, stream>>>(qb, kb, vtb, ob);

  k_gemmo<<<dim3(64, 8), 256, 0, stream>>>(ob, wob, bo, (float*)d_out);
}